// Round 6
// baseline (198.595 us; speedup 1.0000x reference)
//
#include <hip/hip_runtime.h>

#define LAMBDA_COORD 5.0f
#define LAMBDA_NOOBJ 0.5f

// 802816 cells; preds 30 f32/cell (120 B), targets 25 f32/cell (100 B).
// R6: discriminate "load convoys" (H2) vs "per-CU miss-concurrency cap" (H3).
// Each thread handles 2 cells; ALL 30 wide loads are issued before any use
// (sched_barrier(0) fence) -> ~480 B/lane in flight instead of R3's ~32 B
// (VGPR_Count=32 showed the compiler was issuing loads in 2-deep batches).
// No LDS, no nt (R4 showed nt bypasses L3 and doubles HBM fetch).

typedef float f4u __attribute__((ext_vector_type(4), aligned(4)));
typedef float f2u __attribute__((ext_vector_type(2), aligned(4)));

__global__ void zero_out_kernel(float* out, int n) {
    int i = blockIdx.x * blockDim.x + threadIdx.x;
    if (i < n) out[i] = 0.0f;
}

// per-cell loss from 15 loaded vectors (pure register math)
__device__ __forceinline__ float cell_loss(
    f4u P0, f4u P1, f4u P2, f4u P3, f4u P4, f4u P5, f4u P6, f2u P7,
    f4u T0, f4u T1, f4u T2, f4u T3, f4u T4, f4u T5, float t24)
{
    float p0 = P0.x, p5c = P1.y;
    // jnp.argmax picks first index on tie -> box1 only on strict greater.
    bool pick1 = p5c > p0;
    float b0 = pick1 ? p5c  : p0;
    float b1 = pick1 ? P1.z : P0.y;   // p[6] : p[1]
    float b2 = pick1 ? P1.w : P0.z;   // p[7] : p[2]
    float b3 = pick1 ? P2.x : P0.w;   // p[8] : p[3]
    float b4 = pick1 ? P2.y : P1.x;   // p[9] : p[4]

    float t0 = T0.x;
    float d1 = b1 - T0.y, d2 = b2 - T0.z, d3 = b3 - T0.w, d4 = b4 - T1.x;
    float box_loss = d1 * d1 + d2 * d2 + d3 * d3 + d4 * d4;
    float dpc = b0 - t0;
    float pc_loss = dpc * dpc;

    float cl = 0.0f, d;
    d = P2.z - T1.y; cl += d * d;
    d = P2.w - T1.z; cl += d * d;
    d = P3.x - T1.w; cl += d * d;
    d = P3.y - T2.x; cl += d * d;
    d = P3.z - T2.y; cl += d * d;
    d = P3.w - T2.z; cl += d * d;
    d = P4.x - T2.w; cl += d * d;
    d = P4.y - T3.x; cl += d * d;
    d = P4.z - T3.y; cl += d * d;
    d = P4.w - T3.z; cl += d * d;
    d = P5.x - T3.w; cl += d * d;
    d = P5.y - T4.x; cl += d * d;
    d = P5.z - T4.y; cl += d * d;
    d = P5.w - T4.z; cl += d * d;
    d = P6.x - T4.w; cl += d * d;
    d = P6.y - T5.x; cl += d * d;
    d = P6.z - T5.y; cl += d * d;
    d = P6.w - T5.z; cl += d * d;
    d = P7.x - T5.w; cl += d * d;
    d = P7.y - t24;  cl += d * d;

    float obj_term = LAMBDA_COORD * box_loss + pc_loss + cl;
    float noobj_term = LAMBDA_NOOBJ * (p0 * p0 + p5c * p5c);
    return (t0 == 1.0f) ? obj_term : noobj_term;
}

__global__ __launch_bounds__(256) void yolo_loss_kernel(
    const float* __restrict__ preds, const float* __restrict__ targets,
    float* __restrict__ out, int n_cells)
{
    __shared__ float s_part[4];
    const int tid = threadIdx.x;
    const int half = n_cells >> 1;                  // 401408
    const int c0 = blockIdx.x * 256 + tid;          // first cell
    const int c1 = c0 + half;                       // second cell (far stride)

    float loss = 0.0f;
    if (c0 < half) {
        const float* pa = preds + (size_t)c0 * 30;
        const float* ta = targets + (size_t)c0 * 25;
        const float* pb = preds + (size_t)c1 * 30;
        const float* tb = targets + (size_t)c1 * 25;

        // ---- issue ALL 30 loads ----
        const f4u* pa4 = (const f4u*)pa; const f4u* ta4 = (const f4u*)ta;
        const f4u* pb4 = (const f4u*)pb; const f4u* tb4 = (const f4u*)tb;

        f4u aP0 = pa4[0], aP1 = pa4[1], aP2 = pa4[2], aP3 = pa4[3];
        f4u aP4 = pa4[4], aP5 = pa4[5], aP6 = pa4[6];
        f2u aP7 = *(const f2u*)(pa + 28);
        f4u aT0 = ta4[0], aT1 = ta4[1], aT2 = ta4[2], aT3 = ta4[3];
        f4u aT4 = ta4[4], aT5 = ta4[5];
        float at24 = ta[24];

        f4u bP0 = pb4[0], bP1 = pb4[1], bP2 = pb4[2], bP3 = pb4[3];
        f4u bP4 = pb4[4], bP5 = pb4[5], bP6 = pb4[6];
        f2u bP7 = *(const f2u*)(pb + 28);
        f4u bT0 = tb4[0], bT1 = tb4[1], bT2 = tb4[2], bT3 = tb4[3];
        f4u bT4 = tb4[4], bT5 = tb4[5];
        float bt24 = tb[24];

        // fence: no load may sink below, no use may hoist above
        __builtin_amdgcn_sched_barrier(0);

        loss = cell_loss(aP0, aP1, aP2, aP3, aP4, aP5, aP6, aP7,
                         aT0, aT1, aT2, aT3, aT4, aT5, at24)
             + cell_loss(bP0, bP1, bP2, bP3, bP4, bP5, bP6, bP7,
                         bT0, bT1, bT2, bT3, bT4, bT5, bt24);
    }

    // wave (64-lane) shuffle reduction
    #pragma unroll
    for (int off = 32; off > 0; off >>= 1)
        loss += __shfl_down(loss, off, 64);

    const int wave = tid >> 6;
    if ((tid & 63) == 0) s_part[wave] = loss;
    __syncthreads();
    if (tid == 0) {
        float s = s_part[0] + s_part[1] + s_part[2] + s_part[3];
        atomicAdd(out, s);
    }
}

extern "C" void kernel_launch(void* const* d_in, const int* in_sizes, int n_in,
                              void* d_out, int out_size, void* d_ws, size_t ws_size,
                              hipStream_t stream) {
    const float* preds   = (const float*)d_in[0];
    const float* targets = (const float*)d_in[1];
    float* out = (float*)d_out;

    const int n_cells = in_sizes[0] / 30;   // 802816

    // d_out is poisoned (0xAA) before every timed replay — zero it on-stream.
    zero_out_kernel<<<(out_size + 255) / 256, 256, 0, stream>>>(out, out_size);

    const int grid = (n_cells / 2 + 255) / 256; // 1568
    yolo_loss_kernel<<<grid, 256, 0, stream>>>(preds, targets, out, n_cells);
}

// Round 7
// 197.761 us; speedup vs baseline: 1.0042x; 1.0042x over previous
//
#include <hip/hip_runtime.h>

#define LAMBDA_COORD 5.0f
#define LAMBDA_NOOBJ 0.5f

// 802816 cells; preds 30 f32/cell, targets 25 f32/cell.
// R7: the R3/R5/R6 67-us wall is CU-side load-return throughput (~4.3 B/cyc/CU)
// — proven by an L3-resident replay (FETCH~0) running at identical speed.
// Only lever left: request fewer bytes. 70% of cells are noobj and need only
// {t0, p0, p5} (12 B); the other 208 B is loaded under a divergent branch so
// exec-masked lanes issue no requests. Expected ~74 B/cell vs 220 B.

typedef float f4u __attribute__((ext_vector_type(4), aligned(4)));

__global__ void zero_out_kernel(float* out, int n) {
    int i = blockIdx.x * blockDim.x + threadIdx.x;
    if (i < n) out[i] = 0.0f;
}

__global__ __launch_bounds__(256) void yolo_loss_kernel(
    const float* __restrict__ preds, const float* __restrict__ targets,
    float* __restrict__ out, int n_cells)
{
    __shared__ float s_part[4];
    const int tid = threadIdx.x;
    const int c = blockIdx.x * 256 + tid;

    float loss = 0.0f;
    if (c < n_cells) {
        const float* pbase = preds + (size_t)c * 30;
        const float* tbase = targets + (size_t)c * 25;

        // ---- probes: 12 B/cell ----
        float t0 = tbase[0];
        float p0 = pbase[0];
        float p5 = pbase[5];

        if (t0 == 1.0f) {
            // ---- obj path (30% of lanes): 208 B, exec-masked ----
            const f4u B1 = *(const f4u*)(pbase + 1);    // p1..p4
            const f4u B2 = *(const f4u*)(pbase + 6);    // p6..p9
            const f4u C0 = *(const f4u*)(pbase + 10);   // p10..13
            const f4u C1 = *(const f4u*)(pbase + 14);
            const f4u C2 = *(const f4u*)(pbase + 18);
            const f4u C3 = *(const f4u*)(pbase + 22);
            const f4u C4 = *(const f4u*)(pbase + 26);   // p26..29
            const f4u U0 = *(const f4u*)(tbase + 1);    // t1..t4
            const f4u U1 = *(const f4u*)(tbase + 5);    // t5..t8
            const f4u U2 = *(const f4u*)(tbase + 9);
            const f4u U3 = *(const f4u*)(tbase + 13);
            const f4u U4 = *(const f4u*)(tbase + 17);
            const f4u U5 = *(const f4u*)(tbase + 21);   // t21..24

            // jnp.argmax picks first index on tie -> box1 only on strict greater.
            bool pick1 = p5 > p0;
            float b0 = pick1 ? p5 : p0;
            float b1 = pick1 ? B2.x : B1.x;
            float b2 = pick1 ? B2.y : B1.y;
            float b3 = pick1 ? B2.z : B1.z;
            float b4 = pick1 ? B2.w : B1.w;

            float d1 = b1 - U0.x, d2 = b2 - U0.y, d3 = b3 - U0.z, d4 = b4 - U0.w;
            float box_loss = d1 * d1 + d2 * d2 + d3 * d3 + d4 * d4;
            float dpc = b0 - 1.0f;           // t0 == 1 in this branch
            float pc_loss = dpc * dpc;

            float cl = 0.0f, d;
            d = C0.x - U1.x; cl += d * d;
            d = C0.y - U1.y; cl += d * d;
            d = C0.z - U1.z; cl += d * d;
            d = C0.w - U1.w; cl += d * d;
            d = C1.x - U2.x; cl += d * d;
            d = C1.y - U2.y; cl += d * d;
            d = C1.z - U2.z; cl += d * d;
            d = C1.w - U2.w; cl += d * d;
            d = C2.x - U3.x; cl += d * d;
            d = C2.y - U3.y; cl += d * d;
            d = C2.z - U3.z; cl += d * d;
            d = C2.w - U3.w; cl += d * d;
            d = C3.x - U4.x; cl += d * d;
            d = C3.y - U4.y; cl += d * d;
            d = C3.z - U4.z; cl += d * d;
            d = C3.w - U4.w; cl += d * d;
            d = C4.x - U5.x; cl += d * d;
            d = C4.y - U5.y; cl += d * d;
            d = C4.z - U5.z; cl += d * d;
            d = C4.w - U5.w; cl += d * d;

            loss = LAMBDA_COORD * box_loss + pc_loss + cl;
        } else {
            // ---- noobj path (70% of lanes): no further memory ----
            loss = LAMBDA_NOOBJ * (p0 * p0 + p5 * p5);
        }
    }

    // wave (64-lane) shuffle reduction
    #pragma unroll
    for (int off = 32; off > 0; off >>= 1)
        loss += __shfl_down(loss, off, 64);

    const int wave = tid >> 6;
    if ((tid & 63) == 0) s_part[wave] = loss;
    __syncthreads();
    if (tid == 0) {
        float s = s_part[0] + s_part[1] + s_part[2] + s_part[3];
        atomicAdd(out, s);
    }
}

extern "C" void kernel_launch(void* const* d_in, const int* in_sizes, int n_in,
                              void* d_out, int out_size, void* d_ws, size_t ws_size,
                              hipStream_t stream) {
    const float* preds   = (const float*)d_in[0];
    const float* targets = (const float*)d_in[1];
    float* out = (float*)d_out;

    const int n_cells = in_sizes[0] / 30;   // 802816

    // d_out is poisoned (0xAA) before every timed replay — zero it on-stream.
    zero_out_kernel<<<(out_size + 255) / 256, 256, 0, stream>>>(out, out_size);

    const int grid = (n_cells + 255) / 256; // 3136
    yolo_loss_kernel<<<grid, 256, 0, stream>>>(preds, targets, out, n_cells);
}